// Round 6
// baseline (252.091 us; speedup 1.0000x reference)
//
#include <hip/hip_runtime.h>
#include <stdint.h>

// GAT layer on MI355X: B=8, N=2048, F=128.
// h = x@W^T ; s1=h@a1 ; s2=h@a2 ; e=leaky(s1[i]+s2[j]); masked softmax; out=attn@h
// Scores rank-1 (no NxN score GEMM). Floor: adj = 134 MB HBM read ~21 us.
//
// K1 (gat_h): W fp32->bf16 swizzled LDS once/block; split-precision x(hi+lo)
//     MFMA; writes hT in CHUNKED layout (16KB chunks of 64 j, 3-bit XOR
//     swizzle) + s1/s2 in-register.
// K2 (gat_attn): 128-thr blocks, 2 waves; wave = 16 i-rows x all 128 o.
//     adj read once/row (no dup). TJ=64 double-buffered LDS (32 KB/block ->
//     5 blocks/CU; independent barrier domains overlap drains). s2 from
//     global (L1 broadcast). Staging = identity uint4 copy into LDS.

#define B_ 8
#define N_ 2048
#define FD 128
#define ALPHA_ 0.2f
#define TJ 64
#define NCHUNK (N_ / TJ)          // 32
#define CHUNK_U4 1024             // 128 o x 8 u4 per chunk (16 KB)

typedef __attribute__((ext_vector_type(8))) short short8;
typedef __attribute__((ext_vector_type(4))) float f32x4;

// 4-bit XOR swizzle for the 128x128 W tile in gat_h (16B-chunk units)
#define HCHUNK(o, jc) ((((o) * 16) + ((jc) ^ ((o) & 15))) * 8)  // ushort offset
// 3-bit XOR swizzle for 128x64 hT chunks (uint4 units): row o, 16B-chunk jc(0..7)
#define HC64(o, jc) ((o) * 8 + ((jc) ^ ((o) & 7)))              // uint4 index

__device__ __forceinline__ float bf2f(unsigned short u) {
    union { uint32_t i; float f; } v; v.i = ((uint32_t)u) << 16; return v.f;
}
__device__ __forceinline__ unsigned short f2bf(float f) {
    union { float f; uint32_t i; } v; v.f = f;
    uint32_t x = v.i;
    uint32_t r = (x + 0x7fffu + ((x >> 16) & 1u)) >> 16;  // RNE
    return (unsigned short)r;
}

// ---------------------------------------------------------------------------
// Kernel 1: h = x@W^T via split-bf16 MFMA; writes chunked hT + s1/s2.
// 256 blocks x 256 threads; block = 64 rows x 128 outs; wave w: rows w*16..+16.
// A-frag: A[m=lane&15][k=quad*8+jj] = x[row][f];  B-frag: B[k][n]=W[o=n][k].
// C/D: col=lane&15, row=quad*4+reg  (m89/m91-verified layout).
// ---------------------------------------------------------------------------
__global__ __launch_bounds__(256) void gat_h(
    const float* __restrict__ x,
    const float* __restrict__ W,
    const float* __restrict__ a,
    unsigned short* __restrict__ hT,   // chunked: [b][kc][HC64(o,jc)*8 + (j&7)]
    float* __restrict__ s1o, float* __restrict__ s2o)
{
    __shared__ __align__(16) unsigned short Wlds[FD * FD];  // 32KB, swizzled

    const int bid = blockIdx.x;
    const int tid = threadIdx.x;
    const int w = tid >> 6;
    const int lane = tid & 63;
    const int m = lane & 15;
    const int quad = lane >> 4;
    const int arow = bid * 64 + w * 16 + m;   // A-operand row for this lane

    // ---- stage W (fp32 -> bf16) into swizzled LDS, once per block ----
#pragma unroll
    for (int it = 0; it < 8; it++) {
        int cid = it * 256 + tid;          // 2048 16B-chunks
        int o = cid >> 4, kc = cid & 15;
        const float* wp = W + (size_t)o * FD + kc * 8;
        float4 w0 = *(const float4*)wp;
        float4 w1 = *(const float4*)(wp + 4);
        uint4 pk;
        pk.x = (uint32_t)f2bf(w0.x) | ((uint32_t)f2bf(w0.y) << 16);
        pk.y = (uint32_t)f2bf(w0.z) | ((uint32_t)f2bf(w0.w) << 16);
        pk.z = (uint32_t)f2bf(w1.x) | ((uint32_t)f2bf(w1.y) << 16);
        pk.w = (uint32_t)f2bf(w1.z) | ((uint32_t)f2bf(w1.w) << 16);
        *(uint4*)&Wlds[HCHUNK(o, kc)] = pk;
    }
    __syncthreads();

    f32x4 acc[8];
#pragma unroll
    for (int ot = 0; ot < 8; ot++) acc[ot] = (f32x4){0.f, 0.f, 0.f, 0.f};

#pragma unroll
    for (int ks = 0; ks < 4; ks++) {
        const float* xp = x + (size_t)arow * FD + ks * 32 + quad * 8;
        float4 x0 = *(const float4*)xp;
        float4 x1 = *(const float4*)(xp + 4);
        float xv[8] = {x0.x, x0.y, x0.z, x0.w, x1.x, x1.y, x1.z, x1.w};
        union { unsigned short us[8]; short8 v; } ahi, alo;
#pragma unroll
        for (int jj = 0; jj < 8; jj++) {
            unsigned short hi = f2bf(xv[jj]);
            ahi.us[jj] = hi;
            alo.us[jj] = f2bf(xv[jj] - bf2f(hi));
        }
#pragma unroll
        for (int ot = 0; ot < 8; ot++) {
            union { uint4 u; short8 v; } bw;
            bw.u = *(const uint4*)&Wlds[HCHUNK(ot * 16 + m, ks * 4 + quad)];
            acc[ot] = __builtin_amdgcn_mfma_f32_16x16x32_bf16(ahi.v, bw.v, acc[ot], 0, 0, 0);
            acc[ot] = __builtin_amdgcn_mfma_f32_16x16x32_bf16(alo.v, bw.v, acc[ot], 0, 0, 0);
        }
    }

    // Epilogue: store hT (chunked+swizzled, bf16) + s1/s2 partial reduce.
    const int rc0 = bid * 64 + w * 16 + quad * 4;  // C rows rc0..rc0+3 (= j)
    const int bb = rc0 >> 11;                      // batch
    const int jb = rc0 & (N_ - 1);
    const int kc = jb >> 6;                        // chunk
    const int jcl = (jb & 63) >> 3;                // 16B-chunk in chunk
    const int off = jb & 7;                        // 0 or 4 (rc0 % 4 == 0)
    unsigned short* hTb = hT + (size_t)bb * FD * N_ + (size_t)kc * (CHUNK_U4 * 8);
    float s1p[4] = {0.f, 0.f, 0.f, 0.f};
    float s2p[4] = {0.f, 0.f, 0.f, 0.f};
#pragma unroll
    for (int ot = 0; ot < 8; ot++) {
        const int o = ot * 16 + m;
        uint2 pk;
        pk.x = (uint32_t)f2bf(acc[ot][0]) | ((uint32_t)f2bf(acc[ot][1]) << 16);
        pk.y = (uint32_t)f2bf(acc[ot][2]) | ((uint32_t)f2bf(acc[ot][3]) << 16);
        *(uint2*)(hTb + (size_t)HC64(o, jcl) * 8 + off) = pk;
        float a1v = a[o], a2v = a[FD + o];
#pragma unroll
        for (int r = 0; r < 4; r++) {
            s1p[r] += acc[ot][r] * a1v;
            s2p[r] += acc[ot][r] * a2v;
        }
    }
#pragma unroll
    for (int offx = 8; offx >= 1; offx >>= 1) {
#pragma unroll
        for (int r = 0; r < 4; r++) {
            s1p[r] += __shfl_xor(s1p[r], offx);
            s2p[r] += __shfl_xor(s2p[r], offx);
        }
    }
    if (m == 0) {
#pragma unroll
        for (int r = 0; r < 4; r++) {
            s1o[rc0 + r] = s1p[r];
            s2o[rc0 + r] = s2p[r];
        }
    }
}

// ---------------------------------------------------------------------------
// Kernel 2: fused masked-softmax + PV (MFMA).
// 512 blocks (b = bid>>6, i0 = (bid&63)*32) x 128 threads (2 waves).
// Wave w: i-rows [i0 + w*16, +16), ALL 8 o-tiles. adj read once per row.
// Per 64-j chunk: adj int4 reg prefetch (lane layout == A-frag), hT chunk
// identity-copied into LDS double-buffer (1 barrier/chunk), s2 from global.
// LDS = 32 KB -> 5 blocks/CU (independent barrier domains).
// ---------------------------------------------------------------------------
__global__ __launch_bounds__(128) void gat_attn(
    const int* __restrict__ adj,
    const unsigned short* __restrict__ hT,
    const float* __restrict__ s1,
    const float* __restrict__ s2,
    float* __restrict__ out)
{
    __shared__ __align__(16) uint4 hbuf[2][CHUNK_U4];  // 2 x 16 KB

    const int bid = blockIdx.x;
    const int b = bid >> 6;
    const int i0 = (bid & 63) * 32;
    const int tid = threadIdx.x;
    const int lane = tid & 63;
    const int w = tid >> 6;
    const int m = lane & 15;
    const int quad = lane >> 4;

    const int irow = i0 + w * 16 + m;      // this lane's P row (A-frag m)
    const float s1v = s1[b * N_ + irow];
    const int* adjrow = adj + ((size_t)(b * N_ + irow)) * N_;
    const uint4* hTc = (const uint4*)(hT + (size_t)b * FD * N_);  // + k*CHUNK_U4
    const float* s2b = s2 + b * N_;

    // ---- prologue: stage chunk 0 ----
    int4 acur[4];
#pragma unroll
    for (int ks = 0; ks < 2; ks++) {
        acur[2 * ks]     = *(const int4*)(adjrow + ks * 32 + quad * 8);
        acur[2 * ks + 1] = *(const int4*)(adjrow + ks * 32 + quad * 8 + 4);
    }
    {
        uint4 g[8];
#pragma unroll
        for (int it = 0; it < 8; it++) g[it] = hTc[it * 128 + tid];
#pragma unroll
        for (int it = 0; it < 8; it++) hbuf[0][it * 128 + tid] = g[it];
    }
    __syncthreads();

    f32x4 acc[8];
#pragma unroll
    for (int ot = 0; ot < 8; ot++) acc[ot] = (f32x4){0.f, 0.f, 0.f, 0.f};
    float rs_loc = 0.f;

    for (int k = 0; k < NCHUNK; k++) {
        const int buf = k & 1;
        const bool more = (k + 1 < NCHUNK);
        int4 anext[4];
        uint4 gn[8];
        if (more) {
            const int j1 = (k + 1) * TJ;
#pragma unroll
            for (int ks = 0; ks < 2; ks++) {
                anext[2 * ks]     = *(const int4*)(adjrow + j1 + ks * 32 + quad * 8);
                anext[2 * ks + 1] = *(const int4*)(adjrow + j1 + ks * 32 + quad * 8 + 4);
            }
#pragma unroll
            for (int it = 0; it < 8; it++)
                gn[it] = hTc[(size_t)(k + 1) * CHUNK_U4 + it * 128 + tid];
        }

        // ---- compute chunk k ----
#pragma unroll
        for (int ks = 0; ks < 2; ks++) {
            float4 sa = *(const float4*)(s2b + k * TJ + ks * 32 + quad * 8);
            float4 sb = *(const float4*)(s2b + k * TJ + ks * 32 + quad * 8 + 4);
            float sarr[8] = {sa.x, sa.y, sa.z, sa.w, sb.x, sb.y, sb.z, sb.w};
            int4 A0 = acur[2 * ks], A1 = acur[2 * ks + 1];
            int aarr[8] = {A0.x, A0.y, A0.z, A0.w, A1.x, A1.y, A1.z, A1.w};
            union { unsigned short us[8]; short8 v; } af;
#pragma unroll
            for (int jj = 0; jj < 8; jj++) {
                float e = s1v + sarr[jj];
                e = (e > 0.f) ? e : (ALPHA_ * e);
                float p = (aarr[jj] > 0) ? __expf(e) : 0.f;
                rs_loc += p;
                af.us[jj] = f2bf(p);
            }
            const int jc = ks * 4 + quad;  // B-frag 16B-chunk index
#pragma unroll
            for (int ot = 0; ot < 8; ot++) {
                const int o = ot * 16 + m;  // B-frag n = lane&15
                union { uint4 u; short8 v; } bf;
                bf.u = *(const uint4*)&hbuf[buf][HC64(o, jc)];
                acc[ot] = __builtin_amdgcn_mfma_f32_16x16x32_bf16(af.v, bf.v, acc[ot], 0, 0, 0);
            }
        }

        if (more) {
            // buf^1's readers finished before the barrier that closed k-1
#pragma unroll
            for (int it = 0; it < 8; it++) hbuf[buf ^ 1][it * 128 + tid] = gn[it];
            __syncthreads();
#pragma unroll
            for (int q = 0; q < 4; q++) acur[q] = anext[q];
        }
    }

    // ---- row-sum finalize: partials live across quads for same m ----
    rs_loc += __shfl_xor(rs_loc, 16);
    rs_loc += __shfl_xor(rs_loc, 32);
    float rinv[4];
#pragma unroll
    for (int r = 0; r < 4; r++) rinv[r] = 1.0f / __shfl(rs_loc, quad * 4 + r);

    // ---- write: C/D row = quad*4+r, col = ot*16+m ----
    float* outp = out + (size_t)(b * N_ + i0 + w * 16) * FD;
#pragma unroll
    for (int ot = 0; ot < 8; ot++) {
        const int col = ot * 16 + m;
#pragma unroll
        for (int r = 0; r < 4; r++) {
            outp[(size_t)(quad * 4 + r) * FD + col] = acc[ot][r] * rinv[r];
        }
    }
}

// ---------------------------------------------------------------------------
extern "C" void kernel_launch(void* const* d_in, const int* in_sizes, int n_in,
                              void* d_out, int out_size, void* d_ws, size_t ws_size,
                              hipStream_t stream) {
    const void* xv = d_in[0];
    const void* adjv = d_in[1];
    const void* Wv = d_in[2];
    const void* av = d_in[3];
    for (int i = 0; i < n_in; i++) {
        switch (in_sizes[i]) {
            case 2097152:  xv = d_in[i]; break;
            case 33554432: adjv = d_in[i]; break;
            case 16384:    Wv = d_in[i]; break;
            case 256:      av = d_in[i]; break;
            default: break;
        }
    }
    const float* x = (const float*)xv;
    const int* adj = (const int*)adjv;
    const float* W = (const float*)Wv;
    const float* a = (const float*)av;
    float* out = (float*)d_out;

    // ws: hT 4MB | s1 64KB | s2 64KB
    char* p = (char*)d_ws;
    unsigned short* hT = (unsigned short*)p;  p += (size_t)B_ * FD * N_ * 2;
    float* s1 = (float*)p;                    p += (size_t)B_ * N_ * 4;
    float* s2 = (float*)p;

    gat_h<<<256, 256, 0, stream>>>(x, W, a, hT, s1, s2);
    gat_attn<<<512, 128, 0, stream>>>(adj, hT, s1, s2, out);
}

// Round 7
// 217.013 us; speedup vs baseline: 1.1616x; 1.1616x over previous
//
#include <hip/hip_runtime.h>
#include <stdint.h>

// GAT layer on MI355X: B=8, N=2048, F=128.
// h = x@W^T ; s1=h@a1 ; s2=h@a2 ; e=leaky(s1[i]+s2[j]); masked softmax; out=attn@h
// Scores rank-1 (no NxN score GEMM). Floor: adj = 134 MB HBM read ~21 us.
//
// K1 (gat_h): W fp32->bf16 swizzled LDS once/block; split-precision x(hi+lo)
//     MFMA; writes hT in CHUNKED layout (16KB chunks of 64 j, HC64 XOR
//     swizzle baked into GLOBAL layout -> staging is an identity copy).
// K2 (gat_attn): 512 blocks x 256 thr (4 waves, 8 waves/CU). In-block j-split:
//     waves 0,1 = j[0,1024), waves 2,3 = j[1024,2048), same 32 rows; combine
//     via LDS. hT staged with __builtin_amdgcn_global_load_lds (width 16,
//     async, no VGPR round-trip -- R6's 100us was the compiler sinking
//     VGPR-prefetch loads at VGPR_Count=68). adj/s2 prefetched in registers.
//     LDS 64KB -> 2 blocks/CU; SQ_LDS_BANK_CONFLICT=0 with HC64 (R6-measured).

#define B_ 8
#define N_ 2048
#define FD 128
#define ALPHA_ 0.2f
#define TJ 64
#define NCHL 16                   // chunks per j-half (1024/64)
#define CHUNK_U4 1024             // 128 o x 8 u4 per 64-j chunk (16 KB)

typedef __attribute__((ext_vector_type(8))) short short8;
typedef __attribute__((ext_vector_type(4))) float f32x4;

// 4-bit XOR swizzle for the 128x128 W tile in gat_h (16B-chunk units)
#define HCHUNK(o, jc) ((((o) * 16) + ((jc) ^ ((o) & 15))) * 8)  // ushort offset
// 3-bit XOR swizzle for 128x64 hT chunks (uint4 units): row o, 16B-chunk jc(0..7)
#define HC64(o, jc) ((o) * 8 + ((jc) ^ ((o) & 7)))              // uint4 index

__device__ __forceinline__ float bf2f(unsigned short u) {
    union { uint32_t i; float f; } v; v.i = ((uint32_t)u) << 16; return v.f;
}
__device__ __forceinline__ unsigned short f2bf(float f) {
    union { float f; uint32_t i; } v; v.f = f;
    uint32_t x = v.i;
    uint32_t r = (x + 0x7fffu + ((x >> 16) & 1u)) >> 16;  // RNE
    return (unsigned short)r;
}

// async global->LDS, 16B per lane. lds dst must be wave-uniform base;
// HW writes base + lane*16 (m104/m108). Our staging is an identity copy.
__device__ __forceinline__ void gl2lds16(const uint4* g, uint4* l) {
    __builtin_amdgcn_global_load_lds(
        (const __attribute__((address_space(1))) uint32_t*)g,
        (__attribute__((address_space(3))) uint32_t*)l, 16, 0, 0);
}

// ---------------------------------------------------------------------------
// Kernel 1: h = x@W^T via split-bf16 MFMA; writes chunked hT + s1/s2.
// 256 blocks x 256 threads; block = 64 rows x 128 outs; wave w: rows w*16..+16.
// A-frag: A[m=lane&15][k=quad*8+jj] = x[row][f];  B-frag: B[k][n]=W[o=n][k].
// C/D: col=lane&15, row=quad*4+reg  (m89/m91-verified layout).
// ---------------------------------------------------------------------------
__global__ __launch_bounds__(256) void gat_h(
    const float* __restrict__ x,
    const float* __restrict__ W,
    const float* __restrict__ a,
    unsigned short* __restrict__ hT,   // chunked: [b][kc][HC64(o,jc)*8 + (j&7)]
    float* __restrict__ s1o, float* __restrict__ s2o)
{
    __shared__ __align__(16) unsigned short Wlds[FD * FD];  // 32KB, swizzled

    const int bid = blockIdx.x;
    const int tid = threadIdx.x;
    const int w = tid >> 6;
    const int lane = tid & 63;
    const int m = lane & 15;
    const int quad = lane >> 4;
    const int arow = bid * 64 + w * 16 + m;   // A-operand row for this lane

    // ---- stage W (fp32 -> bf16) into swizzled LDS, once per block ----
#pragma unroll
    for (int it = 0; it < 8; it++) {
        int cid = it * 256 + tid;          // 2048 16B-chunks
        int o = cid >> 4, kc = cid & 15;
        const float* wp = W + (size_t)o * FD + kc * 8;
        float4 w0 = *(const float4*)wp;
        float4 w1 = *(const float4*)(wp + 4);
        uint4 pk;
        pk.x = (uint32_t)f2bf(w0.x) | ((uint32_t)f2bf(w0.y) << 16);
        pk.y = (uint32_t)f2bf(w0.z) | ((uint32_t)f2bf(w0.w) << 16);
        pk.z = (uint32_t)f2bf(w1.x) | ((uint32_t)f2bf(w1.y) << 16);
        pk.w = (uint32_t)f2bf(w1.z) | ((uint32_t)f2bf(w1.w) << 16);
        *(uint4*)&Wlds[HCHUNK(o, kc)] = pk;
    }
    __syncthreads();

    f32x4 acc[8];
#pragma unroll
    for (int ot = 0; ot < 8; ot++) acc[ot] = (f32x4){0.f, 0.f, 0.f, 0.f};

#pragma unroll
    for (int ks = 0; ks < 4; ks++) {
        const float* xp = x + (size_t)arow * FD + ks * 32 + quad * 8;
        float4 x0 = *(const float4*)xp;
        float4 x1 = *(const float4*)(xp + 4);
        float xv[8] = {x0.x, x0.y, x0.z, x0.w, x1.x, x1.y, x1.z, x1.w};
        union { unsigned short us[8]; short8 v; } ahi, alo;
#pragma unroll
        for (int jj = 0; jj < 8; jj++) {
            unsigned short hi = f2bf(xv[jj]);
            ahi.us[jj] = hi;
            alo.us[jj] = f2bf(xv[jj] - bf2f(hi));
        }
#pragma unroll
        for (int ot = 0; ot < 8; ot++) {
            union { uint4 u; short8 v; } bw;
            bw.u = *(const uint4*)&Wlds[HCHUNK(ot * 16 + m, ks * 4 + quad)];
            acc[ot] = __builtin_amdgcn_mfma_f32_16x16x32_bf16(ahi.v, bw.v, acc[ot], 0, 0, 0);
            acc[ot] = __builtin_amdgcn_mfma_f32_16x16x32_bf16(alo.v, bw.v, acc[ot], 0, 0, 0);
        }
    }

    // Epilogue: store hT (chunked+swizzled, bf16) + s1/s2 partial reduce.
    const int rc0 = bid * 64 + w * 16 + quad * 4;  // C rows rc0..rc0+3 (= j)
    const int bb = rc0 >> 11;                      // batch
    const int jb = rc0 & (N_ - 1);
    const int kc = jb >> 6;                        // chunk
    const int jcl = (jb & 63) >> 3;                // 16B-chunk in chunk
    const int off = jb & 7;                        // 0 or 4
    unsigned short* hTb = hT + (size_t)bb * FD * N_ + (size_t)kc * (CHUNK_U4 * 8);
    float s1p[4] = {0.f, 0.f, 0.f, 0.f};
    float s2p[4] = {0.f, 0.f, 0.f, 0.f};
#pragma unroll
    for (int ot = 0; ot < 8; ot++) {
        const int o = ot * 16 + m;
        uint2 pk;
        pk.x = (uint32_t)f2bf(acc[ot][0]) | ((uint32_t)f2bf(acc[ot][1]) << 16);
        pk.y = (uint32_t)f2bf(acc[ot][2]) | ((uint32_t)f2bf(acc[ot][3]) << 16);
        *(uint2*)(hTb + (size_t)HC64(o, jcl) * 8 + off) = pk;
        float a1v = a[o], a2v = a[FD + o];
#pragma unroll
        for (int r = 0; r < 4; r++) {
            s1p[r] += acc[ot][r] * a1v;
            s2p[r] += acc[ot][r] * a2v;
        }
    }
#pragma unroll
    for (int offx = 8; offx >= 1; offx >>= 1) {
#pragma unroll
        for (int r = 0; r < 4; r++) {
            s1p[r] += __shfl_xor(s1p[r], offx);
            s2p[r] += __shfl_xor(s2p[r], offx);
        }
    }
    if (m == 0) {
#pragma unroll
        for (int r = 0; r < 4; r++) {
            s1o[rc0 + r] = s1p[r];
            s2o[rc0 + r] = s2p[r];
        }
    }
}

// ---------------------------------------------------------------------------
// Kernel 2: fused masked-softmax + PV (MFMA), in-block j-split.
// 512 blocks (b=bid>>6, i0=(bid&63)*32) x 256 threads (4 waves).
// Wave w: jh = w>>1 (j-half), rh = w&1 (rows-half): rows [i0+rh*16, +16),
// j in [jh*1024, +1024), all 128 o. adj read once per (row, j).
// hT staged via global_load_lds into per-jh double-buffered LDS.
// Epilogue: jh=1 waves push acc/rowsum via LDS; jh=0 combine, divide, write.
// ---------------------------------------------------------------------------
__global__ __launch_bounds__(256, 2) void gat_attn(
    const int* __restrict__ adj,
    const unsigned short* __restrict__ hT,
    const float* __restrict__ s1,
    const float* __restrict__ s2,
    float* __restrict__ out)
{
    __shared__ __align__(16) uint4 hbuf[2][2][CHUNK_U4];  // [jh][buf], 64 KB

    const int bid = blockIdx.x;
    const int b = bid >> 6;
    const int i0 = (bid & 63) * 32;
    const int tid = threadIdx.x;
    const int lane = tid & 63;
    const int w = tid >> 6;
    const int jh = w >> 1;
    const int rh = w & 1;
    const int m = lane & 15;
    const int quad = lane >> 4;

    const int irow = i0 + rh * 16 + m;     // this lane's P row (A-frag m)
    const float s1v = s1[b * N_ + irow];
    const int* adjrow = adj + ((size_t)(b * N_ + irow)) * N_ + jh * 1024;
    const uint4* hTc = (const uint4*)(hT + (size_t)b * FD * N_)
                       + (size_t)jh * NCHL * CHUNK_U4;
    const float* s2b = s2 + b * N_ + jh * 1024;

    // ---- prologue: async-stage chunk 0; prefetch adj/s2 for k=0 ----
#pragma unroll
    for (int it = 0; it < 8; it++)
        gl2lds16(&hTc[it * 128 + rh * 64 + lane], &hbuf[jh][0][it * 128 + rh * 64]);
    int4 acur[4];
    float4 scur[4];
#pragma unroll
    for (int ks = 0; ks < 2; ks++) {
        acur[2 * ks]     = *(const int4*)(adjrow + ks * 32 + quad * 8);
        acur[2 * ks + 1] = *(const int4*)(adjrow + ks * 32 + quad * 8 + 4);
        scur[2 * ks]     = *(const float4*)(s2b + ks * 32 + quad * 8);
        scur[2 * ks + 1] = *(const float4*)(s2b + ks * 32 + quad * 8 + 4);
    }
    __syncthreads();

    f32x4 acc[8];
#pragma unroll
    for (int ot = 0; ot < 8; ot++) acc[ot] = (f32x4){0.f, 0.f, 0.f, 0.f};
    float rs_loc = 0.f;

    for (int k = 0; k < NCHL; k++) {
        const int buf = k & 1;
        const bool more = (k + 1 < NCHL);
        int4 anext[4];
        float4 snext[4];
        if (more) {
            // async-stage chunk k+1 (in flight across compute; barrier drains)
#pragma unroll
            for (int it = 0; it < 8; it++)
                gl2lds16(&hTc[(size_t)(k + 1) * CHUNK_U4 + it * 128 + rh * 64 + lane],
                         &hbuf[jh][buf ^ 1][it * 128 + rh * 64]);
            const int j1 = (k + 1) * TJ;
#pragma unroll
            for (int ks = 0; ks < 2; ks++) {
                anext[2 * ks]     = *(const int4*)(adjrow + j1 + ks * 32 + quad * 8);
                anext[2 * ks + 1] = *(const int4*)(adjrow + j1 + ks * 32 + quad * 8 + 4);
                snext[2 * ks]     = *(const float4*)(s2b + j1 + ks * 32 + quad * 8);
                snext[2 * ks + 1] = *(const float4*)(s2b + j1 + ks * 32 + quad * 8 + 4);
            }
        }

        // ---- compute chunk k ----
#pragma unroll
        for (int ks = 0; ks < 2; ks++) {
            float4 sa = scur[2 * ks], sb = scur[2 * ks + 1];
            float sarr[8] = {sa.x, sa.y, sa.z, sa.w, sb.x, sb.y, sb.z, sb.w};
            int4 A0 = acur[2 * ks], A1 = acur[2 * ks + 1];
            int aarr[8] = {A0.x, A0.y, A0.z, A0.w, A1.x, A1.y, A1.z, A1.w};
            union { unsigned short us[8]; short8 v; } af;
#pragma unroll
            for (int jj = 0; jj < 8; jj++) {
                float e = s1v + sarr[jj];
                e = (e > 0.f) ? e : (ALPHA_ * e);
                float p = (aarr[jj] > 0) ? __expf(e) : 0.f;
                rs_loc += p;
                af.us[jj] = f2bf(p);
            }
            const int jc = ks * 4 + quad;  // B-frag 16B-chunk index
#pragma unroll
            for (int ot = 0; ot < 8; ot++) {
                const int o = ot * 16 + m;  // B-frag n = lane&15
                union { uint4 u; short8 v; } bf;
                bf.u = *(const uint4*)&hbuf[jh][buf][HC64(o, jc)];
                acc[ot] = __builtin_amdgcn_mfma_f32_16x16x32_bf16(af.v, bf.v, acc[ot], 0, 0, 0);
            }
        }

        __syncthreads();  // drains vmcnt(0): chunk k+1 staged; safe to flip
        if (more) {
#pragma unroll
            for (int q = 0; q < 4; q++) { acur[q] = anext[q]; scur[q] = snext[q]; }
        }
    }

    // ---- cross-j-half combine via LDS (reuse hbuf; last barrier above) ----
    float* xch = (float*)&hbuf[0][0][0];   // 16 KB acc + 128 B rowsums
    rs_loc += __shfl_xor(rs_loc, 16);      // sum quads -> every lane: row m sum
    rs_loc += __shfl_xor(rs_loc, 32);
    if (jh == 1) {
#pragma unroll
        for (int ot = 0; ot < 8; ot++)
#pragma unroll
            for (int r = 0; r < 4; r++)
                xch[rh * 2048 + (quad * 4 + r) * 128 + ot * 16 + m] = acc[ot][r];
        if (quad == 0) xch[4096 + rh * 16 + m] = rs_loc;
    }
    __syncthreads();
    if (jh == 0) {
        float rinv[4];
#pragma unroll
        for (int r = 0; r < 4; r++) {
            const int p = quad * 4 + r;
            rinv[r] = 1.0f / (__shfl(rs_loc, p) + xch[4096 + rh * 16 + p]);
        }
        float* outp = out + (size_t)(b * N_ + i0 + rh * 16) * FD;
#pragma unroll
        for (int ot = 0; ot < 8; ot++) {
            const int col = ot * 16 + m;
#pragma unroll
            for (int r = 0; r < 4; r++) {
                float v = acc[ot][r] + xch[rh * 2048 + (quad * 4 + r) * 128 + col];
                outp[(size_t)(quad * 4 + r) * FD + col] = v * rinv[r];
            }
        }
    }
}

// ---------------------------------------------------------------------------
extern "C" void kernel_launch(void* const* d_in, const int* in_sizes, int n_in,
                              void* d_out, int out_size, void* d_ws, size_t ws_size,
                              hipStream_t stream) {
    const void* xv = d_in[0];
    const void* adjv = d_in[1];
    const void* Wv = d_in[2];
    const void* av = d_in[3];
    for (int i = 0; i < n_in; i++) {
        switch (in_sizes[i]) {
            case 2097152:  xv = d_in[i]; break;
            case 33554432: adjv = d_in[i]; break;
            case 16384:    Wv = d_in[i]; break;
            case 256:      av = d_in[i]; break;
            default: break;
        }
    }
    const float* x = (const float*)xv;
    const int* adj = (const int*)adjv;
    const float* W = (const float*)Wv;
    const float* a = (const float*)av;
    float* out = (float*)d_out;

    // ws: hT 4MB | s1 64KB | s2 64KB
    char* p = (char*)d_ws;
    unsigned short* hT = (unsigned short*)p;  p += (size_t)B_ * FD * N_ * 2;
    float* s1 = (float*)p;                    p += (size_t)B_ * N_ * 4;
    float* s2 = (float*)p;

    gat_h<<<256, 256, 0, stream>>>(x, W, a, hT, s1, s2);
    gat_attn<<<512, 256, 0, stream>>>(adj, hT, s1, s2, out);
}